// Round 1
// baseline (139.568 us; speedup 1.0000x reference)
//
#include <hip/hip_runtime.h>

#define D 64

__global__ __launch_bounds__(256, 4)
void gcn_fused_kernel(const float* __restrict__ X,
                      const float* __restrict__ W,
                      const int* __restrict__ rp,
                      const int* __restrict__ col,
                      const float* __restrict__ deg,
                      float* __restrict__ out,
                      int n_nodes)
{
    const int lane = threadIdx.x & 63;
    const int gwave = (int)((blockIdx.x * blockDim.x + threadIdx.x) >> 6);
    const int nwaves = (int)((gridDim.x * blockDim.x) >> 6);

    // Each lane caches its W column: wcol[l] = W[l][lane]. Coalesced (lane
    // contiguous), 64 loads per wave, amortized over ~24 nodes/wave.
    float wcol[D];
#pragma unroll
    for (int l = 0; l < D; ++l) wcol[l] = W[l * D + lane];

    for (int node = gwave; node < n_nodes; node += nwaves) {
        const int start = rp[node];
        const int end   = rp[node + 1];
        const float di  = deg[node];

        // h[lane] = sum_e norm_e * X[src_e][lane]
        float h0 = 0.f, h1 = 0.f, h2 = 0.f, h3 = 0.f;
        const int cnt_total = end - start;

        if (cnt_total == 16) {
            // Fast path (all nodes in this dataset): lanes 0..15 prefetch
            // edge index + norm, broadcast via v_readlane (no LDS/DS traffic).
            int   s_  = (lane < 16) ? col[start + lane] : 0;
            float nm_ = (lane < 16) ? di * deg[s_] : 0.f;
#pragma unroll
            for (int j = 0; j < 16; j += 4) {
                const int s0 = __builtin_amdgcn_readlane(s_, j + 0);
                const int s1 = __builtin_amdgcn_readlane(s_, j + 1);
                const int s2 = __builtin_amdgcn_readlane(s_, j + 2);
                const int s3 = __builtin_amdgcn_readlane(s_, j + 3);
                const float n0 = __uint_as_float(__builtin_amdgcn_readlane(__float_as_uint(nm_), j + 0));
                const float n1 = __uint_as_float(__builtin_amdgcn_readlane(__float_as_uint(nm_), j + 1));
                const float n2 = __uint_as_float(__builtin_amdgcn_readlane(__float_as_uint(nm_), j + 2));
                const float n3 = __uint_as_float(__builtin_amdgcn_readlane(__float_as_uint(nm_), j + 3));
                // 4 independent 256B coalesced row loads in flight
                h0 = fmaf(n0, X[s0 * D + lane], h0);
                h1 = fmaf(n1, X[s1 * D + lane], h1);
                h2 = fmaf(n2, X[s2 * D + lane], h2);
                h3 = fmaf(n3, X[s3 * D + lane], h3);
            }
        } else {
            // General path: chunks of 64 edges
            for (int e0 = start; e0 < end; e0 += 64) {
                const int cnt = min(64, end - e0);
                int   s_  = (lane < cnt) ? col[e0 + lane] : 0;
                float nm_ = (lane < cnt) ? di * deg[s_] : 0.f;
                for (int j = 0; j < cnt; ++j) {
                    const int   sj = __builtin_amdgcn_readlane(s_, j);
                    const float nj = __uint_as_float(__builtin_amdgcn_readlane(__float_as_uint(nm_), j));
                    h0 = fmaf(nj, X[sj * D + lane], h0);
                }
            }
        }
        const float h = (h0 + h1) + (h2 + h3);

        // out[node][lane] = sum_l h[l] * W[l][lane]
        // h[l] broadcast via v_readlane -> SGPR operand of v_fmac.
        float a0 = 0.f, a1 = 0.f, a2 = 0.f, a3 = 0.f;
#pragma unroll
        for (int l = 0; l < D; l += 4) {
            const float b0 = __uint_as_float(__builtin_amdgcn_readlane(__float_as_uint(h), l + 0));
            const float b1 = __uint_as_float(__builtin_amdgcn_readlane(__float_as_uint(h), l + 1));
            const float b2 = __uint_as_float(__builtin_amdgcn_readlane(__float_as_uint(h), l + 2));
            const float b3 = __uint_as_float(__builtin_amdgcn_readlane(__float_as_uint(h), l + 3));
            a0 = fmaf(b0, wcol[l + 0], a0);
            a1 = fmaf(b1, wcol[l + 1], a1);
            a2 = fmaf(b2, wcol[l + 2], a2);
            a3 = fmaf(b3, wcol[l + 3], a3);
        }
        out[(size_t)node * D + lane] = (a0 + a1) + (a2 + a3);
    }
}

extern "C" void kernel_launch(void* const* d_in, const int* in_sizes, int n_in,
                              void* d_out, int out_size, void* d_ws, size_t ws_size,
                              hipStream_t stream) {
    const float* X   = (const float*)d_in[0];
    const float* W   = (const float*)d_in[1];
    const int*   rp  = (const int*)d_in[2];
    const int*   col = (const int*)d_in[3];
    const float* deg = (const float*)d_in[4];
    float* out = (float*)d_out;

    const int n_nodes = in_sizes[4];   // degrees: one per node

    // 1024 blocks x 256 thr = 4096 waves (~4/SIMD), ~24 nodes per wave.
    const int blocks = 1024;
    gcn_fused_kernel<<<blocks, 256, 0, stream>>>(X, W, rp, col, deg, out, n_nodes);
}

// Round 2
// 132.817 us; speedup vs baseline: 1.0508x; 1.0508x over previous
//
#include <hip/hip_runtime.h>
#include <hip/hip_bf16.h>

#define D 64

static __device__ __forceinline__ float bcast_f(float v, int l) {
    return __uint_as_float(__builtin_amdgcn_readlane(__float_as_uint(v), l));
}

// ---------------------------------------------------------------------------
// K1: Y[i][:] = bf16( deg[i] * (X[i][:] @ W) )   — one wave per node.
// lane = output feature. X row broadcast via v_readlane; W column in VGPRs
// (launch_bounds(256,2) leaves room for 64-reg wcol to stay resident).
// ---------------------------------------------------------------------------
__global__ __launch_bounds__(256, 2)
void xw_scale_kernel(const float* __restrict__ X, const float* __restrict__ W,
                     const float* __restrict__ deg, ushort* __restrict__ Y,
                     int n_nodes)
{
    const int lane   = threadIdx.x & 63;
    const int gwave  = (int)((blockIdx.x * blockDim.x + threadIdx.x) >> 6);
    const int nwaves = (int)((gridDim.x * blockDim.x) >> 6);

    float wcol[D];
#pragma unroll
    for (int l = 0; l < D; ++l) wcol[l] = W[l * D + lane];

    for (int node = gwave; node < n_nodes; node += nwaves) {
        const float xr = X[(size_t)node * D + lane];
        const float dn = deg[node];
        float a0 = 0.f, a1 = 0.f, a2 = 0.f, a3 = 0.f;
#pragma unroll
        for (int l = 0; l < D; l += 4) {
            a0 = fmaf(bcast_f(xr, l + 0), wcol[l + 0], a0);
            a1 = fmaf(bcast_f(xr, l + 1), wcol[l + 1], a1);
            a2 = fmaf(bcast_f(xr, l + 2), wcol[l + 2], a2);
            a3 = fmaf(bcast_f(xr, l + 3), wcol[l + 3], a3);
        }
        const float r = ((a0 + a1) + (a2 + a3)) * dn;
        // round-to-nearest-even fp32 -> bf16
        const uint32_t u = __float_as_uint(r);
        Y[(size_t)node * D + lane] = (ushort)((u + 0x7fffu + ((u >> 16) & 1u)) >> 16);
    }
}

// ---------------------------------------------------------------------------
// K2: out[i][:] = deg[i] * sum_e Y[col[e]][:]   — two nodes per wave.
// lanes 0..31 accumulate node A (each lane holds a bf16 pair = 2 features),
// lanes 32..63 accumulate node B. Each gather load is one 512 B transaction
// covering both rows. Edge indices prefetched by lanes 0..31, broadcast via
// v_readlane. deg[src] and the per-edge norm are already folded into Y.
// ---------------------------------------------------------------------------
__global__ __launch_bounds__(256, 4)
void gather_kernel(const ushort* __restrict__ Y, const int* __restrict__ rp,
                   const int* __restrict__ col, const float* __restrict__ deg,
                   float* __restrict__ out, int n_nodes)
{
    const int lane   = threadIdx.x & 63;
    const int gwave  = (int)((blockIdx.x * blockDim.x + threadIdx.x) >> 6);
    const int nwaves = (int)((gridDim.x * blockDim.x) >> 6);
    const int npairs = (n_nodes + 1) >> 1;

    for (int p = gwave; p < npairs; p += nwaves) {
        const int nA = 2 * p, nB = 2 * p + 1;
        const bool hasB = (nB < n_nodes);
        const int a0 = rp[nA], a1 = rp[nA + 1];
        const int b0 = hasB ? rp[nB] : 0;
        const int b1 = hasB ? rp[nB + 1] : 0;

        if ((a1 - a0) == 16 && (!hasB || (b1 - b0) == 16)) {
            // fast path: fixed degree 16 (always true for this dataset)
            int s_ = 0;
            if (lane < 16)        s_ = col[a0 + lane];
            else if (lane < 32)   s_ = hasB ? col[b0 + (lane & 15)] : 0;

            const int half  = lane >> 5;      // 0 = node A, 1 = node B
            const int feat2 = lane & 31;      // which bf16 pair within the row

            float accx = 0.f, accy = 0.f;
#pragma unroll
            for (int j = 0; j < 16; ++j) {
                const int sa = __builtin_amdgcn_readlane(s_, j);
                const int sb = __builtin_amdgcn_readlane(s_, 16 + j);
                const int s  = half ? sb : sa;
                const uint32_t u =
                    *(const uint32_t*)(Y + (size_t)s * D + feat2 * 2);
                accx += __uint_as_float(u << 16);          // low bf16
                accy += __uint_as_float(u & 0xffff0000u);  // high bf16
            }
            const int nd = half ? nB : nA;
            const float dn = (half && !hasB) ? 0.f : deg[nd];
            if (!half || hasB) {
                float2 v; v.x = accx * dn; v.y = accy * dn;
                *(float2*)(out + (size_t)nd * D + feat2 * 2) = v;
            }
        } else {
            // generic fallback (unused for this dataset): lane = feature
            for (int t = 0; t < 2; ++t) {
                const int nd = t ? nB : nA;
                if (nd >= n_nodes) break;
                const int st = rp[nd], en = rp[nd + 1];
                float acc = 0.f;
                for (int e = st; e < en; ++e) {
                    const int s = col[e];
                    const uint32_t w = Y[(size_t)s * D + lane];
                    acc += __uint_as_float(w << 16);
                }
                out[(size_t)nd * D + lane] = acc * deg[nd];
            }
        }
    }
}

// ---------------------------------------------------------------------------
// Fallback (ws too small): round-1 fused kernel, fp32 end-to-end.
// ---------------------------------------------------------------------------
__global__ __launch_bounds__(256, 4)
void gcn_fused_kernel(const float* __restrict__ X, const float* __restrict__ W,
                      const int* __restrict__ rp, const int* __restrict__ col,
                      const float* __restrict__ deg, float* __restrict__ out,
                      int n_nodes)
{
    const int lane   = threadIdx.x & 63;
    const int gwave  = (int)((blockIdx.x * blockDim.x + threadIdx.x) >> 6);
    const int nwaves = (int)((gridDim.x * blockDim.x) >> 6);

    for (int node = gwave; node < n_nodes; node += nwaves) {
        const int start = rp[node];
        const int end   = rp[node + 1];
        const float di  = deg[node];
        float h0 = 0.f, h1 = 0.f, h2 = 0.f, h3 = 0.f;

        for (int e0 = start; e0 < end; e0 += 64) {
            const int cnt = min(64, end - e0);
            int   s_  = (lane < cnt) ? col[e0 + lane] : 0;
            float nm_ = (lane < cnt) ? di * deg[s_] : 0.f;
            for (int j = 0; j < cnt; ++j) {
                const int   sj = __builtin_amdgcn_readlane(s_, j);
                const float nj = bcast_f(nm_, j);
                h0 = fmaf(nj, X[(size_t)sj * D + lane], h0);
            }
        }
        const float h = (h0 + h1) + (h2 + h3);

        float c0 = 0.f, c1 = 0.f, c2 = 0.f, c3 = 0.f;
#pragma unroll
        for (int l = 0; l < D; l += 4) {
            c0 = fmaf(bcast_f(h, l + 0), W[(l + 0) * D + lane], c0);
            c1 = fmaf(bcast_f(h, l + 1), W[(l + 1) * D + lane], c1);
            c2 = fmaf(bcast_f(h, l + 2), W[(l + 2) * D + lane], c2);
            c3 = fmaf(bcast_f(h, l + 3), W[(l + 3) * D + lane], c3);
        }
        out[(size_t)node * D + lane] = (c0 + c1) + (c2 + c3);
    }
}

extern "C" void kernel_launch(void* const* d_in, const int* in_sizes, int n_in,
                              void* d_out, int out_size, void* d_ws, size_t ws_size,
                              hipStream_t stream) {
    const float* X   = (const float*)d_in[0];
    const float* W   = (const float*)d_in[1];
    const int*   rp  = (const int*)d_in[2];
    const int*   col = (const int*)d_in[3];
    const float* deg = (const float*)d_in[4];
    float* out = (float*)d_out;

    const int n_nodes = in_sizes[4];   // degrees: one per node
    const size_t y_bytes = (size_t)n_nodes * D * sizeof(ushort);

    if (ws_size >= y_bytes) {
        ushort* Y = (ushort*)d_ws;
        xw_scale_kernel<<<1024, 256, 0, stream>>>(X, W, deg, Y, n_nodes);
        gather_kernel<<<2048, 256, 0, stream>>>(Y, rp, col, deg, out, n_nodes);
    } else {
        gcn_fused_kernel<<<1024, 256, 0, stream>>>(X, W, rp, col, deg, out, n_nodes);
    }
}